// Round 16
// baseline (166.258 us; speedup 1.0000x reference)
//
#include <hip/hip_runtime.h>

#define NIN    128
#define NOUT   512
#define NBATCH 16384
#define KF     8384            // native feature count
#define KP2    8832            // aligned-padded K order: 16 linear + 1088 cross groups, x8
#define NG     (KP2 / 8)       // 1104 groups
#define NTK2   (KP2 / 64)      // 138 K-tiles (even)
#define NPAIR  (NTK2 / 2)      // 69
#define XSP    136             // xS pitch (f16 elems): 272 B, col 135 = ones
#define NTK    (KF / 64)       // 131 (no-workspace fallback)
#define XP     136
#define AP     72

typedef float f32x4 __attribute__((ext_vector_type(4)));
typedef _Float16 f16x8 __attribute__((ext_vector_type(8)));
typedef _Float16 f16x4 __attribute__((ext_vector_type(4)));
typedef __bf16 bf16x8 __attribute__((ext_vector_type(8)));

__device__ __forceinline__ int triS(int i) { return (i * (257 - i)) >> 1; }

// closed-form K-order table entry (round-3 verified semantics):
// group g -> (i | j0<<16); g<16: linear (i=135 means "ones column")
__device__ __forceinline__ unsigned int tbl_entry(int g)
{
  if (g < 16) return 135u | ((unsigned)(g * 8) << 16);
  int gp = g - 16;
  int b = 0;
  #pragma unroll
  for (int bb = 1; bb <= 15; ++bb) {
    int C = 8 * (16 * bb - bb * (bb - 1) / 2);
    if (gp >= C) b = bb;
  }
  int C   = 8 * (16 * b - b * (b - 1) / 2);
  int r   = gp - C;
  int per = 16 - b;
  int i   = 8 * b + r / per;
  int q   = r % per;
  return (unsigned)i | ((unsigned)(8 * b + 8 * q) << 16);
}

// ======== Wtf: permuted W in per-64n 16x16x32 fragment order =================
// 16B slot idx = ((nb8*138+kt)*8 + kh*4 + ni)*64 + kq*16 + (n&15); holds
// Wperm[kt*64 + kh*32 + kq*8 + e][nb8*64 + ni*16 + (n&15)], e=0..7.
// tbl entries computed ONCE per block (8 groups) and shared via LDS.
__global__ void k_wtf(const float* __restrict__ W, _Float16* __restrict__ Wtf)
{
  __shared__ _Float16 tile[64][65];
  __shared__ unsigned int tg[8];
  const int kb   = blockIdx.x >> 3;    // k-tile 0..137
  const int nbw  = blockIdx.x & 7;     // 64-n block
  const int tid  = threadIdx.x;
  const int lane = tid & 63;
  const int grp  = tid >> 6;
  if (tid < 8) tg[tid] = tbl_entry(kb * 8 + tid);
  __syncthreads();
  #pragma unroll 4
  for (int it = 0; it < 16; ++it) {
    int kl = it * 4 + grp;
    int kp = kb * 64 + kl;
    unsigned int e = tg[kl >> 3];
    int i = (int)(e & 0xFFFFu);
    int j = (int)(e >> 16) + (kp & 7);
    float v = 0.f;
    if (i == 135) {
      v = W[(size_t)kp * NOUT + nbw * 64 + lane];          // linear: kp<128
    } else if (j >= i) {
      int src = 128 + i * 128 - i * (i - 1) / 2 + (j - i); // triu row-major
      v = W[(size_t)src * NOUT + nbw * 64 + lane];
    }
    tile[kl][lane] = (_Float16)v;
  }
  __syncthreads();
  #pragma unroll
  for (int it = 0; it < 2; ++it) {
    int c  = it * 256 + tid;     // 0..511 : (nl, kc)
    int nl = c >> 3;
    int kc = c & 7;              // k-octet: kh = kc>>2, kq = kc&3
    f16x8 v;
    #pragma unroll
    for (int e2 = 0; e2 < 8; ++e2) v[e2] = tile[kc * 8 + e2][nl];
    size_t idx = ((size_t)(nbw * 138 + kb) * 8 + (kc >> 2) * 4 + ((nl >> 4) & 3)) * 64
               + (kc & 3) * 16 + (nl & 15);
    *reinterpret_cast<f16x8*>(Wtf + idx * 8) = v;
  }
}

// ========== main GEMM: 64m x 64n block, 128 thr, 2 k-parity waves ============
// Wave = 64m x 64n over kt === wk (mod 2), 16x16x32 f16 MFMA.
// ~130 regs/wave -> 3 waves/SIMD (12 waves/CU, 6 blocks/CU). B fragment-
// ordered global->reg (bf[2][4], refilled per kh). A generated in regs from
// xS with mi-rotation; setprio around MFMA bursts. NO barriers in K-loop.
__global__ __launch_bounds__(128, 3) void k_gemmE(
    const float* __restrict__ X,
    const _Float16* __restrict__ Wtf,
    const float* __restrict__ bias,
    float* __restrict__ out)
{
  __shared__ __align__(16) _Float16 xS[64 * XSP];    // 17408 B, col135 = 1.0
  __shared__ unsigned short tbl_s[NG];               // 2208 B  (total 19.6 KB)

  const int tid  = threadIdx.x;
  const int lane = tid & 63;
  const int wk   = tid >> 6;          // k-parity
  const int mb   = blockIdx.x >> 3;   // 0..255 (64-row tiles)
  const int nb   = blockIdx.x & 7;    // each XCD sees one 1.13MB Wtf slice

  for (int g = tid; g < NG; g += 128) {
    unsigned int e = tbl_entry(g);
    tbl_s[g] = (unsigned short)((e & 0xFFu) | ((e >> 16) << 8));  // i | j0<<8
  }

  { // stage xS: 64 rows x 128 cols f32 -> f16, + ones column
    const float* xg = X + (size_t)mb * 64 * NIN;
    const int m = tid >> 1, h = tid & 1;
    #pragma unroll
    for (int it = 0; it < 16; ++it) {
      int c4 = h * 64 + it * 4;
      f32x4 v = *reinterpret_cast<const f32x4*>(xg + m * NIN + c4);
      f16x4 b;
      #pragma unroll
      for (int e2 = 0; e2 < 4; ++e2) b[e2] = (_Float16)v[e2];
      *reinterpret_cast<f16x4*>(&xS[m * XSP + c4]) = b;
    }
    if (tid < 64) xS[tid * XSP + 135] = (_Float16)1.0f;
  }
  __syncthreads();   // the ONLY barrier before the epilogue

  // per-mi xS row pointers (loop-invariant)
  const _Float16* xrow[4];
  #pragma unroll
  for (int mi = 0; mi < 4; ++mi)
    xrow[mi] = &xS[(mi * 16 + (lane & 15)) * XSP];

  // B fragment base (f16 units): slot (kt*8 + kh*4 + ni)*512 + lane*8
  const _Float16* wbase = Wtf + (((size_t)(nb * 138) * 8) * 64 + lane) * 8;

  f32x4 acc[4][4];
  #pragma unroll
  for (int a = 0; a < 4; ++a)
    #pragma unroll
    for (int b = 0; b < 4; ++b)
      acc[a][b] = f32x4{0.f, 0.f, 0.f, 0.f};

  f16x8 bf[2][4];
  #pragma unroll
  for (int kh = 0; kh < 2; ++kh)
    #pragma unroll
    for (int ni = 0; ni < 4; ++ni)
      bf[kh][ni] = *reinterpret_cast<const f16x8*>(
          wbase + ((size_t)wk * 8 + kh * 4 + ni) * 512);

  for (int p = 0; p < NPAIR; ++p) {
    const int kt = 2 * p + wk;
    #pragma unroll
    for (int kh = 0; kh < 2; ++kh) {
      unsigned short e = tbl_s[kt * 8 + kh * 4 + (lane >> 4)];
      const int i  = (int)(e & 0xFFu);
      const int j0 = (int)(e >> 8);
      // rotation: mi+1's LDS reads issue before mi's MFMA burst
      f16x8 va = *reinterpret_cast<const f16x8*>(xrow[0] + j0);
      _Float16 sv = xrow[0][i];
      #pragma unroll
      for (int mi = 0; mi < 4; ++mi) {
        f16x8 vc = va;
        _Float16 sc = sv;
        if (mi < 3) {
          va = *reinterpret_cast<const f16x8*>(xrow[mi + 1] + j0);
          sv = xrow[mi + 1][i];
        }
        f16x8 sv8 = {sc, sc, sc, sc, sc, sc, sc, sc};
        f16x8 af = vc * sv8;
        __builtin_amdgcn_s_setprio(1);
        #pragma unroll
        for (int ni = 0; ni < 4; ++ni)
          acc[mi][ni] = __builtin_amdgcn_mfma_f32_16x16x32_f16(
              af, bf[kh][ni], acc[mi][ni], 0, 0, 0);
        __builtin_amdgcn_s_setprio(0);
      }
      // refill bf[kh] for tile kt+2 (used ~1 tile later; covers L2 latency)
      if (p + 1 < NPAIR) {
        #pragma unroll
        for (int ni = 0; ni < 4; ++ni)
          bf[kh][ni] = *reinterpret_cast<const f16x8*>(
              wbase + ((size_t)(kt + 2) * 8 + kh * 4 + ni) * 512);
      }
    }
  }

  // ---- epilogue: k-parity exchange via freed xS (8KB), static acc indices ----
  // C/D 16x16: col=lane&15, row=(lane>>4)*4+q. wk0 stores n 0..31, wk1 n 32..63.
  {
    float* exch = reinterpret_cast<float*>(&xS[0]);
    const int nbase = nb * 64;
    const int mbase = mb * 64;

    __syncthreads();
    if (wk == 1) {                       // round A: wk1 dumps nj 0,1
      #pragma unroll
      for (int mi = 0; mi < 4; ++mi)
        #pragma unroll
        for (int nj = 0; nj < 2; ++nj)
          *reinterpret_cast<f32x4*>(exch + ((mi * 2 + nj) * 64 + lane) * 4) = acc[mi][nj];
    }
    __syncthreads();
    if (wk == 0) {                       // wk0 combines + stores nj 0,1
      #pragma unroll
      for (int nj = 0; nj < 2; ++nj) {
        int n = nbase + nj * 16 + (lane & 15);
        float bv = bias[n];
        #pragma unroll
        for (int mi = 0; mi < 4; ++mi) {
          f32x4 o = *reinterpret_cast<const f32x4*>(exch + ((mi * 2 + nj) * 64 + lane) * 4);
          int mloc = mbase + mi * 16 + ((lane >> 4) << 2);
          #pragma unroll
          for (int q = 0; q < 4; ++q)
            out[(size_t)(mloc + q) * NOUT + n] = acc[mi][nj][q] + o[q] + bv;
        }
      }
    }
    __syncthreads();
    if (wk == 0) {                       // round B: wk0 dumps nj 2,3
      #pragma unroll
      for (int mi = 0; mi < 4; ++mi)
        #pragma unroll
        for (int nj = 0; nj < 2; ++nj)
          *reinterpret_cast<f32x4*>(exch + ((mi * 2 + nj) * 64 + lane) * 4) = acc[mi][2 + nj];
    }
    __syncthreads();
    if (wk == 1) {                       // wk1 combines + stores nj 2,3
      #pragma unroll
      for (int nj = 0; nj < 2; ++nj) {
        int n = nbase + (2 + nj) * 16 + (lane & 15);
        float bv = bias[n];
        #pragma unroll
        for (int mi = 0; mi < 4; ++mi) {
          f32x4 o = *reinterpret_cast<const f32x4*>(exch + ((mi * 2 + nj) * 64 + lane) * 4);
          int mloc = mbase + mi * 16 + ((lane >> 4) << 2);
          #pragma unroll
          for (int q = 0; q < 4; ++q)
            out[(size_t)(mloc + q) * NOUT + n] = acc[mi][2 + nj][q] + o[q] + bv;
        }
      }
    }
  }
}

// ======== no-workspace fallback (r2 pattern; never expected to run) ==========
__global__ __launch_bounds__(256, 2) void k_gemm_nws(
    const float* __restrict__ X, const float* __restrict__ W,
    const float* __restrict__ bias, float* __restrict__ out)
{
  __shared__ __align__(16) __bf16 xT[128 * XP];
  __shared__ __align__(16) __bf16 At[128 * AP];
  __shared__ __align__(16) __bf16 Bt[128 * AP];
  const int tid = threadIdx.x, lane = tid & 63, wid = tid >> 6;
  const int mb = blockIdx.x >> 2, nb = blockIdx.x & 3;
  const int wr = wid >> 1, wc = wid & 1, kk = lane;
  {
    const float* xg = X + (size_t)mb * 128 * 128;
    #pragma unroll
    for (int it = 0; it < 16; ++it) {
      int row = it * 8 + (tid >> 5);
      int c4 = (tid & 31) * 4;
      f32x4 v = *reinterpret_cast<const f32x4*>(xg + row * 128 + c4);
      #pragma unroll
      for (int e = 0; e < 4; ++e) xT[(c4 + e) * XP + row] = (__bf16)v[e];
    }
  }
  f32x4 acc[4][4];
  #pragma unroll
  for (int a = 0; a < 4; ++a)
    #pragma unroll
    for (int b = 0; b < 4; ++b) acc[a][b] = f32x4{0.f, 0.f, 0.f, 0.f};
  __syncthreads();
  for (int kt = 0; kt < NTK; ++kt) {
    #pragma unroll
    for (int rep = 0; rep < 8; ++rep) {
      int r = rep * 8 + (tid >> 5);
      int cL = (tid & 31) * 4;
      f32x4 wv = *reinterpret_cast<const f32x4*>(W + (size_t)(kt * 64 + r) * NOUT + nb * 128 + cL);
      #pragma unroll
      for (int e = 0; e < 4; ++e) Bt[(cL + e) * AP + r] = (__bf16)wv[e];
    }
    const int k = kt * 64 + kk;
    if (kt >= 2) {
      int idx = k - 128;
      int i = (int)((257.0f - sqrtf((float)(66049 - 8 * idx))) * 0.5f);
      if (i < 0) i = 0;
      if (i > 127) i = 127;
      while (i < 127 && triS(i + 1) <= idx) ++i;
      while (i > 0 && triS(i) > idx) --i;
      int j = i + (idx - triS(i));
      #pragma unroll
      for (int mg = 0; mg < 4; ++mg) {
        int m0 = wid * 32 + mg * 8;
        bf16x8 va = *reinterpret_cast<const bf16x8*>(&xT[i * XP + m0]);
        bf16x8 vb = *reinterpret_cast<const bf16x8*>(&xT[j * XP + m0]);
        #pragma unroll
        for (int q = 0; q < 8; ++q)
          At[(m0 + q) * AP + kk] = (__bf16)((float)va[q] * (float)vb[q]);
      }
    } else {
      #pragma unroll
      for (int mg = 0; mg < 4; ++mg) {
        int m0 = wid * 32 + mg * 8;
        bf16x8 va = *reinterpret_cast<const bf16x8*>(&xT[k * XP + m0]);
        #pragma unroll
        for (int q = 0; q < 8; ++q) At[(m0 + q) * AP + kk] = va[q];
      }
    }
    __syncthreads();
    #pragma unroll
    for (int kh = 0; kh < 2; ++kh) {
      const int koff = kh * 32 + 8 * (lane >> 4);
      bf16x8 af2[4], bfv[4];
      #pragma unroll
      for (int mi = 0; mi < 4; ++mi) {
        int m = wr * 64 + mi * 16 + (lane & 15);
        af2[mi] = *reinterpret_cast<const bf16x8*>(&At[m * AP + koff]);
      }
      #pragma unroll
      for (int ni = 0; ni < 4; ++ni) {
        int n = wc * 64 + ni * 16 + (lane & 15);
        bfv[ni] = *reinterpret_cast<const bf16x8*>(&Bt[n * AP + koff]);
      }
      #pragma unroll
      for (int mi = 0; mi < 4; ++mi)
        #pragma unroll
        for (int ni = 0; ni < 4; ++ni)
          acc[mi][ni] = __builtin_amdgcn_mfma_f32_16x16x32_bf16(af2[mi], bfv[ni], acc[mi][ni], 0, 0, 0);
    }
    __syncthreads();
  }
  #pragma unroll
  for (int ni = 0; ni < 4; ++ni) {
    int n = nb * 128 + wc * 64 + ni * 16 + (lane & 15);
    float bv = bias[n];
    #pragma unroll
    for (int mi = 0; mi < 4; ++mi) {
      int mloc = wr * 64 + mi * 16 + ((lane >> 4) << 2);
      #pragma unroll
      for (int q = 0; q < 4; ++q) {
        size_t row = (size_t)mb * 128 + mloc + q;
        out[row * NOUT + n] = acc[mi][ni][q] + bv;
      }
    }
  }
}

extern "C" void kernel_launch(void* const* d_in, const int* in_sizes, int n_in,
                              void* d_out, int out_size, void* d_ws, size_t ws_size,
                              hipStream_t stream)
{
  const float* X    = (const float*)d_in[0];
  const float* W    = (const float*)d_in[1];
  const float* bias = (const float*)d_in[2];
  float* out        = (float*)d_out;

  const size_t wt_bytes = (size_t)NOUT * KP2 * 2;   // 9,043,968 (Wtf fragment order)

  if (d_ws && ws_size >= wt_bytes) {
    _Float16* Wb = (_Float16*)d_ws;
    k_wtf<<<dim3(NTK2 * 8), dim3(256), 0, stream>>>(W, Wb);
    k_gemmE<<<dim3((NBATCH / 64) * 8), dim3(128), 0, stream>>>(X, Wb, bias, out);
  } else {
    k_gemm_nws<<<dim3((NBATCH / 128) * 4), dim3(256), 0, stream>>>(X, W, bias, out);
  }
}

// Round 17
// 142.024 us; speedup vs baseline: 1.1706x; 1.1706x over previous
//
#include <hip/hip_runtime.h>

#define NIN    128
#define NOUT   512
#define NBATCH 16384
#define KF     8384            // native feature count
#define KP2    8832            // aligned-padded K order: 16 linear + 1088 cross groups, x8
#define NG     (KP2 / 8)       // 1104 groups
#define NTK2   (KP2 / 64)      // 138 K-tiles (even)
#define NPAIR  (NTK2 / 2)      // 69
#define XSP    136             // xS pitch (f16 elems): 272 B, col 135 = ones
#define NTK    (KF / 64)       // 131 (no-workspace fallback)
#define XP     136
#define AP     72

typedef float f32x4 __attribute__((ext_vector_type(4)));
typedef _Float16 f16x8 __attribute__((ext_vector_type(8)));
typedef _Float16 f16x4 __attribute__((ext_vector_type(4)));
typedef __bf16 bf16x8 __attribute__((ext_vector_type(8)));

__device__ __forceinline__ int triS(int i) { return (i * (257 - i)) >> 1; }

// closed-form K-order table entry (round-3 verified semantics):
// group g -> (i | j0<<16); g<16: linear (i=135 means "ones column")
__device__ __forceinline__ unsigned int tbl_entry(int g)
{
  if (g < 16) return 135u | ((unsigned)(g * 8) << 16);
  int gp = g - 16;
  int b = 0;
  #pragma unroll
  for (int bb = 1; bb <= 15; ++bb) {
    int C = 8 * (16 * bb - bb * (bb - 1) / 2);
    if (gp >= C) b = bb;
  }
  int C   = 8 * (16 * b - b * (b - 1) / 2);
  int r   = gp - C;
  int per = 16 - b;
  int i   = 8 * b + r / per;
  int q   = r % per;
  return (unsigned)i | ((unsigned)(8 * b + 8 * q) << 16);
}

// ======== Wtf: permuted W in 16x16x32 MFMA-fragment order (r11/r12 layout) ====
// 16B slot idx = ((nb*138+kt)*16 + chunk)*64 + slot, chunk = kh*8 + ni',
// slot = kq*16 + (n&15); holds Wperm[kt*64 + kh*32 + kq*8 + e][n], e=0..7.
// tbl entries computed ONCE per block (8 groups, r16-verified speedup).
__global__ void k_wtf(const float* __restrict__ W, _Float16* __restrict__ Wtf)
{
  __shared__ _Float16 tile[64][65];
  __shared__ unsigned int tg[8];
  const int kb   = blockIdx.x >> 3;    // k-tile 0..137
  const int nbw  = blockIdx.x & 7;     // 64-n block
  const int tid  = threadIdx.x;
  const int lane = tid & 63;
  const int grp  = tid >> 6;
  if (tid < 8) tg[tid] = tbl_entry(kb * 8 + tid);
  __syncthreads();
  #pragma unroll 4
  for (int it = 0; it < 16; ++it) {
    int kl = it * 4 + grp;
    int kp = kb * 64 + kl;
    unsigned int e = tg[kl >> 3];
    int i = (int)(e & 0xFFFFu);
    int j = (int)(e >> 16) + (kp & 7);
    float v = 0.f;
    if (i == 135) {
      v = W[(size_t)kp * NOUT + nbw * 64 + lane];          // linear: kp<128
    } else if (j >= i) {
      int src = 128 + i * 128 - i * (i - 1) / 2 + (j - i); // triu row-major
      v = W[(size_t)src * NOUT + nbw * 64 + lane];
    }
    tile[kl][lane] = (_Float16)v;
  }
  __syncthreads();
  #pragma unroll
  for (int it = 0; it < 2; ++it) {
    int c  = it * 256 + tid;     // 0..511 : (nl, kc)
    int nl = c >> 3;
    int kc = c & 7;
    int n  = nbw * 64 + nl;
    f16x8 v;
    #pragma unroll
    for (int e2 = 0; e2 < 8; ++e2) v[e2] = tile[kc * 8 + e2][nl];
    size_t idx = ((size_t)((n >> 7) * 138 + kb) * 16 + ((kc >> 2) * 8 + ((n >> 4) & 7))) * 64
               + ((kc & 3) * 16 + (n & 15));
    *reinterpret_cast<f16x8*>(Wtf + idx * 8) = v;
  }
}

// ========== main GEMM (r15-verified, 128.4 us): r12 structure + setprio ======
// 128m x 128n block, 256 thr, 4 waves (wm, wk). Wave = 64m x 128n over
// kt === wk (mod 2), 16x16x32 f16 MFMA. B fragment-ordered global->reg
// (bf[2][8], refilled per kh). A generated in regs from xS; mi+1's LDS reads
// issued before mi's MFMA burst; MFMA bursts wrapped in s_setprio(1).
// NO barriers in the K-loop. 2 blocks/CU, 2 waves/SIMD.
__global__ __launch_bounds__(256, 2) void k_gemmD(
    const float* __restrict__ X,
    const _Float16* __restrict__ Wtf,
    const float* __restrict__ bias,
    float* __restrict__ out)
{
  __shared__ __align__(16) _Float16 xS[128 * XSP];   // 34816 B, col135 = 1.0
  __shared__ unsigned short tbl_s[NG];               // 2208 B  (total 37 KB)

  const int tid  = threadIdx.x;
  const int lane = tid & 63;
  const int wid  = tid >> 6;
  const int wm   = wid & 1;           // m-half (64 rows)
  const int wk   = wid >> 1;          // k-parity
  const int mb   = blockIdx.x >> 2;
  const int nb   = blockIdx.x & 3;    // each XCD sees one 2.26MB Wtf slice

  for (int g = tid; g < NG; g += 256) {
    unsigned int e = tbl_entry(g);
    tbl_s[g] = (unsigned short)((e & 0xFFu) | ((e >> 16) << 8));  // i | j0<<8
  }

  { // stage xS (row-major f16) + ones column
    const float* xg = X + (size_t)mb * 128 * NIN;
    const int m = tid >> 1, h = tid & 1;
    #pragma unroll
    for (int it = 0; it < 16; ++it) {
      int c4 = h * 64 + it * 4;
      f32x4 v = *reinterpret_cast<const f32x4*>(xg + m * NIN + c4);
      f16x4 b;
      #pragma unroll
      for (int e2 = 0; e2 < 4; ++e2) b[e2] = (_Float16)v[e2];
      *reinterpret_cast<f16x4*>(&xS[m * XSP + c4]) = b;
    }
    if (tid < 128) xS[tid * XSP + 135] = (_Float16)1.0f;
  }
  __syncthreads();   // the ONLY barrier before the epilogue

  // per-mi xS row pointers (loop-invariant)
  const _Float16* xrow[4];
  #pragma unroll
  for (int mi = 0; mi < 4; ++mi)
    xrow[mi] = &xS[(wm * 64 + mi * 16 + (lane & 15)) * XSP];

  // B fragment base (f16 units): slot (kt*16 + kh*8 + ni)*512 + lane*8
  const _Float16* wbase = Wtf + (((size_t)(nb * 138) * 16) * 64 + lane) * 8;

  f32x4 acc[4][8];
  #pragma unroll
  for (int a = 0; a < 4; ++a)
    #pragma unroll
    for (int b = 0; b < 8; ++b)
      acc[a][b] = f32x4{0.f, 0.f, 0.f, 0.f};

  f16x8 bf[2][8];
  #pragma unroll
  for (int kh = 0; kh < 2; ++kh)
    #pragma unroll
    for (int ni = 0; ni < 8; ++ni)
      bf[kh][ni] = *reinterpret_cast<const f16x8*>(
          wbase + ((size_t)wk * 16 + kh * 8 + ni) * 512);

  for (int p = 0; p < NPAIR; ++p) {
    const int kt = 2 * p + wk;
    #pragma unroll
    for (int kh = 0; kh < 2; ++kh) {
      unsigned short e = tbl_s[kt * 8 + kh * 4 + (lane >> 4)];
      const int i  = (int)(e & 0xFFu);
      const int j0 = (int)(e >> 8);
      // seed reads for mi=0; rotate: mi+1's reads issue before mi's MFMAs
      f16x8 va = *reinterpret_cast<const f16x8*>(xrow[0] + j0);
      _Float16 sv = xrow[0][i];
      #pragma unroll
      for (int mi = 0; mi < 4; ++mi) {
        f16x8 vc = va;
        _Float16 sc = sv;
        if (mi < 3) {   // prefetch next mi (latency hides under MFMA burst)
          va = *reinterpret_cast<const f16x8*>(xrow[mi + 1] + j0);
          sv = xrow[mi + 1][i];
        }
        f16x8 sv8 = {sc, sc, sc, sc, sc, sc, sc, sc};
        f16x8 af = vc * sv8;
        __builtin_amdgcn_s_setprio(1);
        #pragma unroll
        for (int ni = 0; ni < 8; ++ni)
          acc[mi][ni] = __builtin_amdgcn_mfma_f32_16x16x32_f16(
              af, bf[kh][ni], acc[mi][ni], 0, 0, 0);
        __builtin_amdgcn_s_setprio(0);
      }
      // refill bf[kh] for tile kt+2 (used ~2 kh-phases later, ~550 cyc)
      if (p + 1 < NPAIR) {
        #pragma unroll
        for (int ni = 0; ni < 8; ++ni)
          bf[kh][ni] = *reinterpret_cast<const f16x8*>(
              wbase + ((size_t)(kt + 2) * 16 + kh * 8 + ni) * 512);
      }
    }
  }

  // ---- epilogue: k-parity exchange via xS, 2 rounds, static acc indices ----
  // (r12-verified; C/D 16x16: col=lane&15, row=(lane>>4)*4+q)
  {
    float* exch = reinterpret_cast<float*>(&xS[0]) + wm * 4096;   // 16 KB/region
    const int nbase = nb * 128;
    const int mbase = mb * 128 + wm * 64;

    __syncthreads();                     // all waves done with xS
    if (wk == 1) {                       // round A: wk1 dumps nj 0..3
      #pragma unroll
      for (int mi = 0; mi < 4; ++mi)
        #pragma unroll
        for (int nj = 0; nj < 4; ++nj)
          *reinterpret_cast<f32x4*>(exch + ((mi * 4 + nj) * 64 + lane) * 4) = acc[mi][nj];
    }
    __syncthreads();
    if (wk == 0) {                       // wk0 combines + stores nj 0..3
      #pragma unroll
      for (int nj = 0; nj < 4; ++nj) {
        int n = nbase + nj * 16 + (lane & 15);
        float bv = bias[n];
        #pragma unroll
        for (int mi = 0; mi < 4; ++mi) {
          f32x4 o = *reinterpret_cast<const f32x4*>(exch + ((mi * 4 + nj) * 64 + lane) * 4);
          int mloc = mbase + mi * 16 + ((lane >> 4) << 2);
          #pragma unroll
          for (int q = 0; q < 4; ++q)
            out[(size_t)(mloc + q) * NOUT + n] = acc[mi][nj][q] + o[q] + bv;
        }
      }
    }
    __syncthreads();
    if (wk == 0) {                       // round B: wk0 dumps nj 4..7
      #pragma unroll
      for (int mi = 0; mi < 4; ++mi)
        #pragma unroll
        for (int nj = 0; nj < 4; ++nj)
          *reinterpret_cast<f32x4*>(exch + ((mi * 4 + nj) * 64 + lane) * 4) = acc[mi][4 + nj];
    }
    __syncthreads();
    if (wk == 1) {                       // wk1 combines + stores nj 4..7
      #pragma unroll
      for (int nj = 0; nj < 4; ++nj) {
        int n = nbase + (4 + nj) * 16 + (lane & 15);
        float bv = bias[n];
        #pragma unroll
        for (int mi = 0; mi < 4; ++mi) {
          f32x4 o = *reinterpret_cast<const f32x4*>(exch + ((mi * 4 + nj) * 64 + lane) * 4);
          int mloc = mbase + mi * 16 + ((lane >> 4) << 2);
          #pragma unroll
          for (int q = 0; q < 4; ++q)
            out[(size_t)(mloc + q) * NOUT + n] = acc[mi][4 + nj][q] + o[q] + bv;
        }
      }
    }
  }
}

// ======== no-workspace fallback (r2 pattern; never expected to run) ==========
__global__ __launch_bounds__(256, 2) void k_gemm_nws(
    const float* __restrict__ X, const float* __restrict__ W,
    const float* __restrict__ bias, float* __restrict__ out)
{
  __shared__ __align__(16) __bf16 xT[128 * XP];
  __shared__ __align__(16) __bf16 At[128 * AP];
  __shared__ __align__(16) __bf16 Bt[128 * AP];
  const int tid = threadIdx.x, lane = tid & 63, wid = tid >> 6;
  const int mb = blockIdx.x >> 2, nb = blockIdx.x & 3;
  const int wr = wid >> 1, wc = wid & 1, kk = lane;
  {
    const float* xg = X + (size_t)mb * 128 * 128;
    #pragma unroll
    for (int it = 0; it < 16; ++it) {
      int row = it * 8 + (tid >> 5);
      int c4 = (tid & 31) * 4;
      f32x4 v = *reinterpret_cast<const f32x4*>(xg + row * 128 + c4);
      #pragma unroll
      for (int e = 0; e < 4; ++e) xT[(c4 + e) * XP + row] = (__bf16)v[e];
    }
  }
  f32x4 acc[4][4];
  #pragma unroll
  for (int a = 0; a < 4; ++a)
    #pragma unroll
    for (int b = 0; b < 4; ++b) acc[a][b] = f32x4{0.f, 0.f, 0.f, 0.f};
  __syncthreads();
  for (int kt = 0; kt < NTK; ++kt) {
    #pragma unroll
    for (int rep = 0; rep < 8; ++rep) {
      int r = rep * 8 + (tid >> 5);
      int cL = (tid & 31) * 4;
      f32x4 wv = *reinterpret_cast<const f32x4*>(W + (size_t)(kt * 64 + r) * NOUT + nb * 128 + cL);
      #pragma unroll
      for (int e = 0; e < 4; ++e) Bt[(cL + e) * AP + r] = (__bf16)wv[e];
    }
    const int k = kt * 64 + kk;
    if (kt >= 2) {
      int idx = k - 128;
      int i = (int)((257.0f - sqrtf((float)(66049 - 8 * idx))) * 0.5f);
      if (i < 0) i = 0;
      if (i > 127) i = 127;
      while (i < 127 && triS(i + 1) <= idx) ++i;
      while (i > 0 && triS(i) > idx) --i;
      int j = i + (idx - triS(i));
      #pragma unroll
      for (int mg = 0; mg < 4; ++mg) {
        int m0 = wid * 32 + mg * 8;
        bf16x8 va = *reinterpret_cast<const bf16x8*>(&xT[i * XP + m0]);
        bf16x8 vb = *reinterpret_cast<const bf16x8*>(&xT[j * XP + m0]);
        #pragma unroll
        for (int q = 0; q < 8; ++q)
          At[(m0 + q) * AP + kk] = (__bf16)((float)va[q] * (float)vb[q]);
      }
    } else {
      #pragma unroll
      for (int mg = 0; mg < 4; ++mg) {
        int m0 = wid * 32 + mg * 8;
        bf16x8 va = *reinterpret_cast<const bf16x8*>(&xT[k * XP + m0]);
        #pragma unroll
        for (int q = 0; q < 8; ++q) At[(m0 + q) * AP + kk] = va[q];
      }
    }
    __syncthreads();
    #pragma unroll
    for (int kh = 0; kh < 2; ++kh) {
      const int koff = kh * 32 + 8 * (lane >> 4);
      bf16x8 af2[4], bfv[4];
      #pragma unroll
      for (int mi = 0; mi < 4; ++mi) {
        int m = wr * 64 + mi * 16 + (lane & 15);
        af2[mi] = *reinterpret_cast<const bf16x8*>(&At[m * AP + koff]);
      }
      #pragma unroll
      for (int ni = 0; ni < 4; ++ni) {
        int n = wc * 64 + ni * 16 + (lane & 15);
        bfv[ni] = *reinterpret_cast<const bf16x8*>(&Bt[n * AP + koff]);
      }
      #pragma unroll
      for (int mi = 0; mi < 4; ++mi)
        #pragma unroll
        for (int ni = 0; ni < 4; ++ni)
          acc[mi][ni] = __builtin_amdgcn_mfma_f32_16x16x32_bf16(af2[mi], bfv[ni], acc[mi][ni], 0, 0, 0);
    }
    __syncthreads();
  }
  #pragma unroll
  for (int ni = 0; ni < 4; ++ni) {
    int n = nb * 128 + wc * 64 + ni * 16 + (lane & 15);
    float bv = bias[n];
    #pragma unroll
    for (int mi = 0; mi < 4; ++mi) {
      int mloc = wr * 64 + mi * 16 + ((lane >> 4) << 2);
      #pragma unroll
      for (int q = 0; q < 4; ++q) {
        size_t row = (size_t)mb * 128 + mloc + q;
        out[row * NOUT + n] = acc[mi][ni][q] + bv;
      }
    }
  }
}

extern "C" void kernel_launch(void* const* d_in, const int* in_sizes, int n_in,
                              void* d_out, int out_size, void* d_ws, size_t ws_size,
                              hipStream_t stream)
{
  const float* X    = (const float*)d_in[0];
  const float* W    = (const float*)d_in[1];
  const float* bias = (const float*)d_in[2];
  float* out        = (float*)d_out;

  const size_t wt_bytes = (size_t)NOUT * KP2 * 2;   // 9,043,968 (Wtf fragment order)

  if (d_ws && ws_size >= wt_bytes) {
    _Float16* Wb = (_Float16*)d_ws;
    k_wtf<<<dim3(NTK2 * 8), dim3(256), 0, stream>>>(W, Wb);
    k_gemmD<<<dim3((NBATCH / 128) * 4), dim3(256), 0, stream>>>(X, Wb, bias, out);
  } else {
    k_gemm_nws<<<dim3((NBATCH / 128) * 4), dim3(256), 0, stream>>>(X, W, bias, out);
  }
}